// Round 15
// baseline (964.742 us; speedup 1.0000x reference)
//
#include <hip/hip_runtime.h>
#include <hip/hip_bf16.h>

typedef __bf16 bf16_t;
typedef __attribute__((ext_vector_type(8))) __bf16 bf16x8;
typedef __attribute__((ext_vector_type(4))) float f32x4;

constexpr int IN_F  = 4096;
constexpr int OUT_F = 16384;
constexpr int N_TOK = 8192;
constexpr int KSEL  = 8192;
constexpr long A_ELEMS = (long)N_TOK * IN_F;

constexpr int BM = 256, BN = 256, BK = 32;
constexpr int NT = IN_F / BK;        // 128 K-tiles

#define GLOBAL_CAST(p) (const __attribute__((address_space(1))) void*)(p)
#define LDS_CAST(p)    (__attribute__((address_space(3))) void*)(p)

// ---------------------------------------------------------------------------
// Kernel 1: idx[] = positions of mask==1 (ascending) + gather bias (fp32).
// ---------------------------------------------------------------------------
__global__ __launch_bounds__(1024) void build_idx_kernel(
    const int* __restrict__ mask, const float* __restrict__ bias,
    int* __restrict__ idx, float* __restrict__ bsel)
{
    const int t    = threadIdx.x;
    const int lane = t & 63;
    const int wave = t >> 6;
    const int base_i = t * 16;

    int m[16];
    const int4* mp = (const int4*)(mask + base_i);
#pragma unroll
    for (int v = 0; v < 4; ++v) {
        int4 q = mp[v];
        m[v*4+0] = q.x; m[v*4+1] = q.y; m[v*4+2] = q.z; m[v*4+3] = q.w;
    }
    int cnt = 0;
#pragma unroll
    for (int j = 0; j < 16; ++j) cnt += (m[j] != 0) ? 1 : 0;

    int incl = cnt;
#pragma unroll
    for (int d = 1; d < 64; d <<= 1) {
        int o = __shfl_up(incl, (unsigned)d);
        if (lane >= d) incl += o;
    }

    __shared__ int wsum[16];
    __shared__ int wbase[16];
    if (lane == 63) wsum[wave] = incl;
    __syncthreads();
    if (t == 0) {
        int s = 0;
        for (int w = 0; w < 16; ++w) { wbase[w] = s; s += wsum[w]; }
    }
    __syncthreads();

    int p = wbase[wave] + (incl - cnt);
#pragma unroll
    for (int j = 0; j < 16; ++j) {
        if (m[j]) {
            int i = base_i + j;
            idx[p]  = i;
            bsel[p] = bias[i];
            ++p;
        }
    }
}

// ---------------------------------------------------------------------------
// Kernel 2: fp32 -> bf16 convert; A straight, W gathered by idx.
// ---------------------------------------------------------------------------
__global__ __launch_bounds__(256) void convert_kernel(
    const float* __restrict__ A, const float* __restrict__ W,
    const int* __restrict__ idx,
    bf16_t* __restrict__ Ab, bf16_t* __restrict__ Wb)
{
    const long nvecA = A_ELEMS / 8;
    const long total = nvecA * 2;
    const long stride = (long)gridDim.x * blockDim.x;
    for (long v = (long)blockIdx.x * blockDim.x + threadIdx.x; v < total; v += stride) {
        const float4* src;
        bf16_t* dst;
        if (v < nvecA) {
            src = (const float4*)(A + v * 8);
            dst = Ab + v * 8;
        } else {
            long u = v - nvecA;
            int j = (int)(u >> 9);
            int k = (int)(u & 511) * 8;
            src = (const float4*)(W + (long)idx[j] * IN_F + k);
            dst = Wb + u * 8;
        }
        float4 x = src[0], y = src[1];
        bf16x8 o;
        o[0]=(bf16_t)x.x; o[1]=(bf16_t)x.y; o[2]=(bf16_t)x.z; o[3]=(bf16_t)x.w;
        o[4]=(bf16_t)y.x; o[5]=(bf16_t)y.y; o[6]=(bf16_t)y.z; o[7]=(bf16_t)y.w;
        *(bf16x8*)dst = o;
    }
}

// ---------------------------------------------------------------------------
// Kernel 3: 16-WAVE (1024-thread) 256x256, BK=32, ring-of-4 LDS buffers.
// Per wave: 64x64 output -> acc 64 regs (vs 128 at 8-wave), total ~120 VGPR
// -> 4 waves/SIMD resident -> TLP overlap of ds_read and MFMA across waves
// (m114). r5's verified ring schedule: ONE barrier + counted vmcnt per
// K-tile (stage runs 2 tiles ahead; buf (t+2)&3 last read at t-2). Pair-row
// XOR swizzle (BK=32, conflicts=0 measured r5) via pre-swizzled global
// source + swizzled read bases. Flat LDS + x4 loop unroll -> ring indices
// are literals -> all ds_reads are base + compile-time imm (r12 lesson).
// ---------------------------------------------------------------------------
__global__ __launch_bounds__(1024, 4) void gemm16w_kernel(
    const bf16_t* __restrict__ A, const bf16_t* __restrict__ B,
    const float* __restrict__ bsel, float* __restrict__ C)
{
    __shared__ __attribute__((aligned(16))) char lds[131072];

    const int tid  = threadIdx.x;
    const int w    = tid >> 6;          // wave 0..15
    const int lane = tid & 63;
    const int wr   = w >> 2;            // 0..3 -> 64-row A strip
    const int wc   = w & 3;             // 0..3 -> 64-col B strip

    // XCD swizzle: n-panel chunk per XCD, m fastest (1024 % 8 == 0)
    const int bid = blockIdx.x;
    const int swz = (bid & 7) * 128 + (bid >> 3);
    const int m0 = (swz & 31) * BM;
    const int n0 = (swz >> 5) * BN;

    // staging source (inverse pair-row swizzle; LDS dest linear).
    // lane l -> phys pair prl=l>>3, phys slot l&7 holds logical slot sl^prl.
    const int prl = lane >> 3;
    const int sl  = (lane & 7) ^ prl;
    const int srow_off = 2 * prl + (sl >> 2);   // 0..15
    const int scol     = (sl & 3) * 8;
    const bf16_t* aSrc = A + (long)(m0 + w * 16 + srow_off) * IN_F + scol;
    const bf16_t* bSrc = B + (long)(n0 + w * 16 + srow_off) * IN_F + scol;

// one load covers this wave's 16 rows (64 lanes x 16B = 1024B = 16 x 64B rows)
#define STAGE(buf, tl) do {                                                    \
    __builtin_amdgcn_global_load_lds(GLOBAL_CAST(aSrc + (long)(tl) * BK),      \
        LDS_CAST(lds + (buf) * 16384 + w * 1024), 16, 0, 0);                   \
    __builtin_amdgcn_global_load_lds(GLOBAL_CAST(bSrc + (long)(tl) * BK),      \
        LDS_CAST(lds + 65536 + (buf) * 16384 + w * 1024), 16, 0, 0);           \
} while (0)

    f32x4 acc[4][4];
#pragma unroll
    for (int m = 0; m < 4; ++m)
#pragma unroll
        for (int n = 0; n < 4; ++n)
#pragma unroll
            for (int j = 0; j < 4; ++j) acc[m][n][j] = 0.f;

    const int fr    = lane & 15;
    const int kslot = lane >> 4;
    // logical (row fr within frag, kslot) -> phys slot within 128B pair-row
    const int swz_b = ((((fr & 1) << 2) | kslot) ^ ((fr >> 1) & 7)) * 16;
    // per-thread loop-invariant byte bases (buf and frag offsets are imms)
    const int aBase = (wr * 32 + (fr >> 1)) * 128 + swz_b;
    const int bBase = 65536 + (wc * 32 + (fr >> 1)) * 128 + swz_b;

#define VMC2() asm volatile("s_waitcnt vmcnt(2)" ::: "memory")
#define VMC0() asm volatile("s_waitcnt vmcnt(0)" ::: "memory")
#define BAR()  __builtin_amdgcn_s_barrier()

#define ITER(t, cb, sb) do {                                                   \
    const bool st = ((t) + 2 < NT);                                            \
    bf16x8 af[4], bg[4];                                                       \
    _Pragma("unroll") for (int m = 0; m < 4; ++m)                              \
        af[m] = *(const bf16x8*)(lds + (cb) * 16384 + aBase + m * 1024);       \
    _Pragma("unroll") for (int n = 0; n < 4; ++n)                              \
        bg[n] = *(const bf16x8*)(lds + (cb) * 16384 + bBase + n * 1024);       \
    if (st) STAGE((sb), (t) + 2);                                              \
    __builtin_amdgcn_s_setprio(1);                                             \
    _Pragma("unroll") for (int m = 0; m < 4; ++m)                              \
    _Pragma("unroll") for (int n = 0; n < 4; ++n)                              \
        acc[m][n] = __builtin_amdgcn_mfma_f32_16x16x32_bf16(                   \
            af[m], bg[n], acc[m][n], 0, 0, 0);                                 \
    __builtin_amdgcn_s_setprio(0);                                             \
    if (st) VMC2(); else VMC0();                                               \
    BAR();                                                                     \
} while (0)

    // prologue: stage tiles 0,1; drain tile 0 (keep tile 1's 2 loads in flight)
    STAGE(0, 0); STAGE(1, 1);
    VMC2(); BAR();

    for (int I = 0; I < NT; I += 4) {
        ITER(I + 0, 0, 2);
        ITER(I + 1, 1, 3);
        ITER(I + 2, 2, 0);
        ITER(I + 3, 3, 1);
    }

#undef ITER
#undef STAGE
#undef VMC2
#undef VMC0
#undef BAR

    // epilogue: +bias, fp32 store (verified mapping, r5 geometry)
    float b4[4];
#pragma unroll
    for (int n = 0; n < 4; ++n) b4[n] = bsel[n0 + wc * 64 + n * 16 + fr];

    const int rbase = m0 + wr * 64 + kslot * 4;
#pragma unroll
    for (int m = 0; m < 4; ++m)
#pragma unroll
        for (int n = 0; n < 4; ++n) {
            const int col = n0 + wc * 64 + n * 16 + fr;
#pragma unroll
            for (int j = 0; j < 4; ++j)
                C[(long)(rbase + m * 16 + j) * KSEL + col] = acc[m][n][j] + b4[n];
        }
}

// ---------------------------------------------------------------------------
// Fallback (ws too small): fp32-staged m97-structure GEMM (known-correct).
// ---------------------------------------------------------------------------
__global__ __launch_bounds__(256) void gemm_f32staged_kernel(
    const float* __restrict__ A, const float* __restrict__ W,
    const int* __restrict__ idx, const float* __restrict__ bsel,
    float* __restrict__ C)
{
    constexpr int FBM = 128, FBN = 128, BK2 = 32;
    __shared__ __attribute__((aligned(16))) float Asf[FBM * BK2];
    __shared__ __attribute__((aligned(16))) float Bsf[FBN * BK2];

    const int tid  = threadIdx.x;
    const int wave = tid >> 6;
    const int lane = tid & 63;
    const int wrf  = wave >> 1;
    const int wcf  = wave & 1;

    const int m0 = blockIdx.x * FBM;
    const int n0 = blockIdx.y * FBN;

    const int srow = lane >> 3;
    const int scol = (lane & 7) * 4;

    const float* aptr[4];
    const float* bptr[4];
#pragma unroll
    for (int i = 0; i < 4; ++i) {
        aptr[i] = A + (long)(m0 + wave * 32 + i * 8 + srow) * IN_F + scol;
        const int br = idx[n0 + wave * 32 + i * 8 + srow];
        bptr[i] = W + (long)br * IN_F + scol;
    }

    f32x4 acc[4][4];
#pragma unroll
    for (int m = 0; m < 4; ++m)
#pragma unroll
        for (int n = 0; n < 4; ++n)
#pragma unroll
            for (int j = 0; j < 4; ++j) acc[m][n][j] = 0.f;

    const int fr = lane & 15;
    const int fk = (lane >> 4) * 8;

    for (int k0 = 0; k0 < IN_F; k0 += BK2) {
#pragma unroll
        for (int i = 0; i < 4; ++i) {
            __builtin_amdgcn_global_load_lds(GLOBAL_CAST(aptr[i] + k0),
                LDS_CAST(&Asf[(wave * 32 + i * 8) * BK2]), 16, 0, 0);
            __builtin_amdgcn_global_load_lds(GLOBAL_CAST(bptr[i] + k0),
                LDS_CAST(&Bsf[(wave * 32 + i * 8) * BK2]), 16, 0, 0);
        }
        __syncthreads();

        bf16x8 af[4], bg[4];
#pragma unroll
        for (int m = 0; m < 4; ++m) {
            const float* p = &Asf[(wrf * 64 + m * 16 + fr) * BK2 + fk];
            f32x4 x = *(const f32x4*)p, y = *(const f32x4*)(p + 4);
#pragma unroll
            for (int j = 0; j < 4; ++j) { af[m][j] = (bf16_t)x[j]; af[m][4+j] = (bf16_t)y[j]; }
        }
#pragma unroll
        for (int n = 0; n < 4; ++n) {
            const float* p = &Bsf[(wcf * 64 + n * 16 + fr) * BK2 + fk];
            f32x4 x = *(const f32x4*)p, y = *(const f32x4*)(p + 4);
#pragma unroll
            for (int j = 0; j < 4; ++j) { bg[n][j] = (bf16_t)x[j]; bg[n][4+j] = (bf16_t)y[j]; }
        }
#pragma unroll
        for (int m = 0; m < 4; ++m)
#pragma unroll
            for (int n = 0; n < 4; ++n)
                acc[m][n] = __builtin_amdgcn_mfma_f32_16x16x32_bf16(
                    af[m], bg[n], acc[m][n], 0, 0, 0);
        __syncthreads();
    }

    float b4[4];
#pragma unroll
    for (int n = 0; n < 4; ++n) b4[n] = bsel[n0 + wcf * 64 + n * 16 + fr];

    const int rbase = m0 + wrf * 64 + (lane >> 4) * 4;
#pragma unroll
    for (int m = 0; m < 4; ++m)
#pragma unroll
        for (int n = 0; n < 4; ++n) {
            const int col = n0 + wcf * 64 + n * 16 + fr;
#pragma unroll
            for (int j = 0; j < 4; ++j)
                C[(long)(rbase + m * 16 + j) * KSEL + col] = acc[m][n][j] + b4[n];
        }
}

// ---------------------------------------------------------------------------
extern "C" void kernel_launch(void* const* d_in, const int* in_sizes, int n_in,
                              void* d_out, int out_size, void* d_ws, size_t ws_size,
                              hipStream_t stream)
{
    const float* data   = (const float*)d_in[0];
    const float* weight = (const float*)d_in[1];
    const float* bias   = (const float*)d_in[2];
    const int*   mask   = (const int*)d_in[3];
    float*       out    = (float*)d_out;

    char* ws = (char*)d_ws;
    int*   idx  = (int*)ws;
    float* bsel = (float*)(ws + (KSEL * 4));
    bf16_t* Ab  = (bf16_t*)(ws + (KSEL * 8));
    bf16_t* Wb  = Ab + A_ELEMS;

    const size_t NEED = (size_t)KSEL * 8 + (size_t)A_ELEMS * 2 * 2;

    build_idx_kernel<<<1, 1024, 0, stream>>>(mask, bias, idx, bsel);

    if (ws_size >= NEED) {
        convert_kernel<<<4096, 256, 0, stream>>>(data, weight, idx, Ab, Wb);
        gemm16w_kernel<<<1024, 1024, 0, stream>>>(Ab, Wb, bsel, out);
    } else {
        dim3 grid(N_TOK / 128, KSEL / 128);
        gemm_f32staged_kernel<<<grid, 256, 0, stream>>>(data, weight, idx, bsel, out);
    }
}

// Round 16
// 678.348 us; speedup vs baseline: 1.4222x; 1.4222x over previous
//
#include <hip/hip_runtime.h>
#include <hip/hip_bf16.h>

typedef __bf16 bf16_t;
typedef __attribute__((ext_vector_type(8))) __bf16 bf16x8;
typedef __attribute__((ext_vector_type(4))) float f32x4;

constexpr int IN_F  = 4096;
constexpr int OUT_F = 16384;
constexpr int N_TOK = 8192;
constexpr int KSEL  = 8192;
constexpr long A_ELEMS = (long)N_TOK * IN_F;

constexpr int BM = 256, BN = 256, BK = 64;
constexpr int NT = IN_F / BK;        // 64 K-tiles

#define GLOBAL_CAST(p) (const __attribute__((address_space(1))) void*)(p)
#define LDS_CAST(p)    (__attribute__((address_space(3))) void*)(p)

// ---------------------------------------------------------------------------
// Kernel 1: idx[] = positions of mask==1 (ascending) + gather bias (fp32).
// ---------------------------------------------------------------------------
__global__ __launch_bounds__(1024) void build_idx_kernel(
    const int* __restrict__ mask, const float* __restrict__ bias,
    int* __restrict__ idx, float* __restrict__ bsel)
{
    const int t    = threadIdx.x;
    const int lane = t & 63;
    const int wave = t >> 6;
    const int base_i = t * 16;

    int m[16];
    const int4* mp = (const int4*)(mask + base_i);
#pragma unroll
    for (int v = 0; v < 4; ++v) {
        int4 q = mp[v];
        m[v*4+0] = q.x; m[v*4+1] = q.y; m[v*4+2] = q.z; m[v*4+3] = q.w;
    }
    int cnt = 0;
#pragma unroll
    for (int j = 0; j < 16; ++j) cnt += (m[j] != 0) ? 1 : 0;

    int incl = cnt;
#pragma unroll
    for (int d = 1; d < 64; d <<= 1) {
        int o = __shfl_up(incl, (unsigned)d);
        if (lane >= d) incl += o;
    }

    __shared__ int wsum[16];
    __shared__ int wbase[16];
    if (lane == 63) wsum[wave] = incl;
    __syncthreads();
    if (t == 0) {
        int s = 0;
        for (int w = 0; w < 16; ++w) { wbase[w] = s; s += wsum[w]; }
    }
    __syncthreads();

    int p = wbase[wave] + (incl - cnt);
#pragma unroll
    for (int j = 0; j < 16; ++j) {
        if (m[j]) {
            int i = base_i + j;
            idx[p]  = i;
            bsel[p] = bias[i];
            ++p;
        }
    }
}

// ---------------------------------------------------------------------------
// Kernel 2: fp32 -> bf16 convert; A straight, W gathered by idx.
// ---------------------------------------------------------------------------
__global__ __launch_bounds__(256) void convert_kernel(
    const float* __restrict__ A, const float* __restrict__ W,
    const int* __restrict__ idx,
    bf16_t* __restrict__ Ab, bf16_t* __restrict__ Wb)
{
    const long nvecA = A_ELEMS / 8;
    const long total = nvecA * 2;
    const long stride = (long)gridDim.x * blockDim.x;
    for (long v = (long)blockIdx.x * blockDim.x + threadIdx.x; v < total; v += stride) {
        const float4* src;
        bf16_t* dst;
        if (v < nvecA) {
            src = (const float4*)(A + v * 8);
            dst = Ab + v * 8;
        } else {
            long u = v - nvecA;
            int j = (int)(u >> 9);
            int k = (int)(u & 511) * 8;
            src = (const float4*)(W + (long)idx[j] * IN_F + k);
            dst = Wb + u * 8;
        }
        float4 x = src[0], y = src[1];
        bf16x8 o;
        o[0]=(bf16_t)x.x; o[1]=(bf16_t)x.y; o[2]=(bf16_t)x.z; o[3]=(bf16_t)x.w;
        o[4]=(bf16_t)y.x; o[5]=(bf16_t)y.y; o[6]=(bf16_t)y.z; o[7]=(bf16_t)y.w;
        *(bf16x8*)dst = o;
    }
}

// ---------------------------------------------------------------------------
// Kernel 3 (= round-12/14, best measured: 582-586us GEMM / ~940 TF):
// r8 8-phase 256x256 BK=64 schedule + PRECOMPUTED LDS read bases (flat
// 128KB LDS; per-buf {A-h0 @0, A-h1 @16K, B-h0 @32K, B-h1 @48K}, buf1 @
// +64K; all in-loop ds_reads are base + compile-time-const -> offset imm).
// Stagger: ph3 stages B(t+2), ph4 A(t+2), ph7 B(u+2), ph8 A(u+2);
// vmcnt(8) at ph4/ph8 (tail: vmcnt(0) at ph4). XOR slot swizzle via
// pre-swizzled global source (conflicts=0 measured). Single frag set.
// Measured-dead alternatives: reg ping-pong spills (r13 -39%), 32x32 MFMA
// re-conflicts (r11 -22%), 2x128^2 blocks (r10 -37%), 16-wave (r15 -52%).
// ---------------------------------------------------------------------------
__global__ __launch_bounds__(512, 2) void gemm8p_kernel(
    const bf16_t* __restrict__ A, const bf16_t* __restrict__ B,
    const float* __restrict__ bsel, float* __restrict__ C)
{
    __shared__ __attribute__((aligned(16))) char lds[131072];

    const int tid  = threadIdx.x;
    const int w    = tid >> 6;
    const int lane = tid & 63;
    const int wr   = w >> 2;            // 0..1 -> 128-row A strip (= A half)
    const int wc   = w & 3;             // 0..3 -> 64-col B strip (half = wc>>1)

    // XCD swizzle: n-panel chunk per XCD, m fastest (1024 % 8 == 0)
    const int bid = blockIdx.x;
    const int swz = (bid & 7) * 128 + (bid >> 3);
    const int m0 = (swz & 31) * BM;
    const int n0 = (swz >> 5) * BN;

    // staging source (inverse XOR slot swizzle; LDS dest linear)
    const int pr  = lane >> 3;                  // phys row within 8-row load
    const int csw = ((lane & 7) ^ pr) * 8;      // logical col for phys slot
    const bf16_t* aSrc[2][2];
    const bf16_t* bSrc[2][2];
#pragma unroll
    for (int h = 0; h < 2; ++h)
#pragma unroll
        for (int j = 0; j < 2; ++j) {
            const int row = h * 128 + (w * 2 + j) * 8 + pr;
            aSrc[h][j] = A + (long)(m0 + row) * IN_F + csw;
            bSrc[h][j] = B + (long)(n0 + row) * IN_F + csw;
        }

// LDS byte offsets: buf*65536 + {A: h*16384 | B: 32768 + h*16384} + sub*1024
#define ST_A(buf, h, tl) do {                                                  \
    __builtin_amdgcn_global_load_lds(GLOBAL_CAST(aSrc[h][0] + (long)(tl)*BK),  \
        LDS_CAST(lds + (buf)*65536 + (h)*16384 + w*2048), 16, 0, 0);           \
    __builtin_amdgcn_global_load_lds(GLOBAL_CAST(aSrc[h][1] + (long)(tl)*BK),  \
        LDS_CAST(lds + (buf)*65536 + (h)*16384 + w*2048 + 1024), 16, 0, 0);    \
} while (0)
#define ST_B(buf, h, tl) do {                                                  \
    __builtin_amdgcn_global_load_lds(GLOBAL_CAST(bSrc[h][0] + (long)(tl)*BK),  \
        LDS_CAST(lds + (buf)*65536 + 32768 + (h)*16384 + w*2048), 16, 0, 0);   \
    __builtin_amdgcn_global_load_lds(GLOBAL_CAST(bSrc[h][1] + (long)(tl)*BK),  \
        LDS_CAST(lds + (buf)*65536 + 32768 + (h)*16384 + w*2048 + 1024),       \
        16, 0, 0);                                                             \
} while (0)

    f32x4 acc[8][4];
#pragma unroll
    for (int m = 0; m < 8; ++m)
#pragma unroll
        for (int n = 0; n < 4; ++n)
#pragma unroll
            for (int j = 0; j < 4; ++j) acc[m][n][j] = 0.f;

    const int fr    = lane & 15;
    const int kslot = lane >> 4;
    // swizzled slot BYTE offsets for kk=0 / kk=32
    const int sp0b = ((kslot       ^ (fr & 7)) << 4);
    const int sp1b = (((4 + kslot) ^ (fr & 7)) << 4);

    // precomputed per-thread read bases (bytes into lds) — loop-invariant
    const int a0s0 = wr * 16384 + fr * 128 + sp0b;            // A, buf0, k-half0
    const int a0s1 = wr * 16384 + fr * 128 + sp1b;
    const int a1s0 = a0s0 + 65536;
    const int a1s1 = a0s1 + 65536;
    const int bbase = 32768 + (wc >> 1) * 16384 + ((wc & 1) * 64 + fr) * 128;
    const int b0s0 = bbase + sp0b;
    const int b0s1 = bbase + sp1b;
    const int b1s0 = b0s0 + 65536;
    const int b1s1 = b0s1 + 65536;

    bf16x8 af[4][2], bg[4][2];

// reads: base + const imm only (mq*8192 + mm*2048 / (nh*2+nn)*2048)
#define RDA(s0, s1, mq) do {                                                   \
    _Pragma("unroll") for (int mm = 0; mm < 4; ++mm) {                         \
        af[mm][0] = *(const bf16x8*)(lds + (s0) + (mq)*8192 + mm*2048);        \
        af[mm][1] = *(const bf16x8*)(lds + (s1) + (mq)*8192 + mm*2048);        \
    } } while (0)
#define RDB(s0, s1, nh) do {                                                   \
    _Pragma("unroll") for (int nn = 0; nn < 2; ++nn) {                         \
        bg[(nh)*2+nn][0] = *(const bf16x8*)(lds + (s0) + ((nh)*2+nn)*2048);    \
        bg[(nh)*2+nn][1] = *(const bf16x8*)(lds + (s1) + ((nh)*2+nn)*2048);    \
    } } while (0)
#define MFMAQ(mq, nh) do {                                                     \
    __builtin_amdgcn_s_setprio(1);                                             \
    _Pragma("unroll") for (int mm = 0; mm < 4; ++mm)                           \
    _Pragma("unroll") for (int nn = 0; nn < 2; ++nn) {                         \
        const int m = (mq) * 4 + mm, n = (nh) * 2 + nn;                        \
        acc[m][n] = __builtin_amdgcn_mfma_f32_16x16x32_bf16(                   \
            af[mm][0], bg[n][0], acc[m][n], 0, 0, 0);                          \
        acc[m][n] = __builtin_amdgcn_mfma_f32_16x16x32_bf16(                   \
            af[mm][1], bg[n][1], acc[m][n], 0, 0, 0);                          \
    }                                                                          \
    __builtin_amdgcn_s_setprio(0); } while (0)
#define BAR()    __builtin_amdgcn_s_barrier()
#define LGKM0()  asm volatile("s_waitcnt lgkmcnt(0)" ::: "memory")
#define LGKMH()  asm volatile("s_waitcnt lgkmcnt(8)" ::: "memory")
#define VMC8()   asm volatile("s_waitcnt vmcnt(8)" ::: "memory")
#define VMC0()   asm volatile("s_waitcnt vmcnt(0)" ::: "memory")

    // prologue: stage tiles 0 and 1 fully (16 loads); drain tile 0, keep 1
    ST_A(0, 0, 0); ST_A(0, 1, 0); ST_B(0, 0, 0); ST_B(0, 1, 0);
    ST_A(1, 0, 1); ST_A(1, 1, 1); ST_B(1, 0, 1); ST_B(1, 1, 1);
    VMC8(); BAR();

    for (int I = 0; I < NT / 2; ++I) {
        const int t = 2 * I, u = t + 1;          // t -> buf0, u -> buf1
        const bool s2 = (I < NT / 2 - 1);

        // ph1 (t,mq0,nh0): 12 ds_read
        RDA(a0s0, a0s1, 0); RDB(b0s0, b0s1, 0);
        LGKMH(); BAR(); LGKM0(); MFMAQ(0, 0); BAR();
        // ph2 (t,mq0,nh1): 4 ds_read  [last read of B(t)]
        RDB(b0s0, b0s1, 1);
        BAR(); LGKM0(); MFMAQ(0, 1); BAR();
        // ph3 (t,mq1,nh0): 8 ds_read [last read of A(t)] + stage B(t+2)
        RDA(a0s0, a0s1, 1);
        if (s2) { ST_B(0, 0, t + 2); ST_B(0, 1, t + 2); }
        BAR(); LGKM0(); MFMAQ(1, 0); BAR();
        // ph4 (t,mq1,nh1): stage A(t+2); boundary wait -> tile t+1 landed
        if (s2) { ST_A(0, 0, t + 2); ST_A(0, 1, t + 2); }
        BAR(); MFMAQ(1, 1); if (s2) VMC8(); else VMC0(); BAR();
        // ph5 (u,mq0,nh0): 12 ds_read
        RDA(a1s0, a1s1, 0); RDB(b1s0, b1s1, 0);
        LGKMH(); BAR(); LGKM0(); MFMAQ(0, 0); BAR();
        // ph6 (u,mq0,nh1): 4 ds_read  [last read of B(u)]
        RDB(b1s0, b1s1, 1);
        BAR(); LGKM0(); MFMAQ(0, 1); BAR();
        // ph7 (u,mq1,nh0): 8 ds_read [last read of A(u)] + stage B(u+2)
        RDA(a1s0, a1s1, 1);
        if (s2) { ST_B(1, 0, u + 2); ST_B(1, 1, u + 2); }
        BAR(); LGKM0(); MFMAQ(1, 0); BAR();
        // ph8 (u,mq1,nh1): stage A(u+2); boundary wait -> tile t+2 landed
        if (s2) { ST_A(1, 0, u + 2); ST_A(1, 1, u + 2); }
        BAR(); MFMAQ(1, 1); if (s2) VMC8(); else VMC0(); BAR();
    }
    VMC0();

#undef ST_A
#undef ST_B
#undef RDA
#undef RDB
#undef MFMAQ
#undef BAR
#undef LGKM0
#undef LGKMH
#undef VMC8
#undef VMC0

    // epilogue: +bias, fp32 store (mapping verified rounds 3-14)
    float b4[4];
#pragma unroll
    for (int n = 0; n < 4; ++n) b4[n] = bsel[n0 + wc * 64 + n * 16 + fr];

    const int rbase = m0 + wr * 128 + kslot * 4;
#pragma unroll
    for (int m = 0; m < 8; ++m)
#pragma unroll
        for (int n = 0; n < 4; ++n) {
            const int col = n0 + wc * 64 + n * 16 + fr;
#pragma unroll
            for (int j = 0; j < 4; ++j)
                C[(long)(rbase + m * 16 + j) * KSEL + col] = acc[m][n][j] + b4[n];
        }
}

// ---------------------------------------------------------------------------
// Fallback (ws too small): fp32-staged m97-structure GEMM (known-correct).
// ---------------------------------------------------------------------------
__global__ __launch_bounds__(256) void gemm_f32staged_kernel(
    const float* __restrict__ A, const float* __restrict__ W,
    const int* __restrict__ idx, const float* __restrict__ bsel,
    float* __restrict__ C)
{
    constexpr int FBM = 128, FBN = 128, BK2 = 32;
    __shared__ __attribute__((aligned(16))) float Asf[FBM * BK2];
    __shared__ __attribute__((aligned(16))) float Bsf[FBN * BK2];

    const int tid  = threadIdx.x;
    const int wave = tid >> 6;
    const int lane = tid & 63;
    const int wrf  = wave >> 1;
    const int wcf  = wave & 1;

    const int m0 = blockIdx.x * FBM;
    const int n0 = blockIdx.y * FBN;

    const int srow = lane >> 3;
    const int scol = (lane & 7) * 4;

    const float* aptr[4];
    const float* bptr[4];
#pragma unroll
    for (int i = 0; i < 4; ++i) {
        aptr[i] = A + (long)(m0 + wave * 32 + i * 8 + srow) * IN_F + scol;
        const int br = idx[n0 + wave * 32 + i * 8 + srow];
        bptr[i] = W + (long)br * IN_F + scol;
    }

    f32x4 acc[4][4];
#pragma unroll
    for (int m = 0; m < 4; ++m)
#pragma unroll
        for (int n = 0; n < 4; ++n)
#pragma unroll
            for (int j = 0; j < 4; ++j) acc[m][n][j] = 0.f;

    const int fr = lane & 15;
    const int fk = (lane >> 4) * 8;

    for (int k0 = 0; k0 < IN_F; k0 += BK2) {
#pragma unroll
        for (int i = 0; i < 4; ++i) {
            __builtin_amdgcn_global_load_lds(GLOBAL_CAST(aptr[i] + k0),
                LDS_CAST(&Asf[(wave * 32 + i * 8) * BK2]), 16, 0, 0);
            __builtin_amdgcn_global_load_lds(GLOBAL_CAST(bptr[i] + k0),
                LDS_CAST(&Bsf[(wave * 32 + i * 8) * BK2]), 16, 0, 0);
        }
        __syncthreads();

        bf16x8 af[4], bg[4];
#pragma unroll
        for (int m = 0; m < 4; ++m) {
            const float* p = &Asf[(wrf * 64 + m * 16 + fr) * BK2 + fk];
            f32x4 x = *(const f32x4*)p, y = *(const f32x4*)(p + 4);
#pragma unroll
            for (int j = 0; j < 4; ++j) { af[m][j] = (bf16_t)x[j]; af[m][4+j] = (bf16_t)y[j]; }
        }
#pragma unroll
        for (int n = 0; n < 4; ++n) {
            const float* p = &Bsf[(wcf * 64 + n * 16 + fr) * BK2 + fk];
            f32x4 x = *(const f32x4*)p, y = *(const f32x4*)(p + 4);
#pragma unroll
            for (int j = 0; j < 4; ++j) { bg[n][j] = (bf16_t)x[j]; bg[n][4+j] = (bf16_t)y[j]; }
        }
#pragma unroll
        for (int m = 0; m < 4; ++m)
#pragma unroll
            for (int n = 0; n < 4; ++n)
                acc[m][n] = __builtin_amdgcn_mfma_f32_16x16x32_bf16(
                    af[m], bg[n], acc[m][n], 0, 0, 0);
        __syncthreads();
    }

    float b4[4];
#pragma unroll
    for (int n = 0; n < 4; ++n) b4[n] = bsel[n0 + wcf * 64 + n * 16 + fr];

    const int rbase = m0 + wrf * 64 + (lane >> 4) * 4;
#pragma unroll
    for (int m = 0; m < 4; ++m)
#pragma unroll
        for (int n = 0; n < 4; ++n) {
            const int col = n0 + wcf * 64 + n * 16 + fr;
#pragma unroll
            for (int j = 0; j < 4; ++j)
                C[(long)(rbase + m * 16 + j) * KSEL + col] = acc[m][n][j] + b4[n];
        }
}

// ---------------------------------------------------------------------------
extern "C" void kernel_launch(void* const* d_in, const int* in_sizes, int n_in,
                              void* d_out, int out_size, void* d_ws, size_t ws_size,
                              hipStream_t stream)
{
    const float* data   = (const float*)d_in[0];
    const float* weight = (const float*)d_in[1];
    const float* bias   = (const float*)d_in[2];
    const int*   mask   = (const int*)d_in[3];
    float*       out    = (float*)d_out;

    char* ws = (char*)d_ws;
    int*   idx  = (int*)ws;
    float* bsel = (float*)(ws + (KSEL * 4));
    bf16_t* Ab  = (bf16_t*)(ws + (KSEL * 8));
    bf16_t* Wb  = Ab + A_ELEMS;

    const size_t NEED = (size_t)KSEL * 8 + (size_t)A_ELEMS * 2 * 2;

    build_idx_kernel<<<1, 1024, 0, stream>>>(mask, bias, idx, bsel);

    if (ws_size >= NEED) {
        convert_kernel<<<4096, 256, 0, stream>>>(data, weight, idx, Ab, Wb);
        gemm8p_kernel<<<1024, 512, 0, stream>>>(Ab, Wb, bsel, out);
    } else {
        dim3 grid(N_TOK / 128, KSEL / 128);
        gemm_f32staged_kernel<<<grid, 256, 0, stream>>>(data, weight, idx, bsel, out);
    }
}